// Round 11
// baseline (430.084 us; speedup 1.0000x reference)
//
#include <hip/hip_runtime.h>
#include <math.h>

// Problem constants (from setup_inputs)
#define N_NODES  100000
#define N_EDGES  2000000
#define HID      40
#define N_GRAPHS 512

// dst-bucketing: 64 nodes per bucket, 8 sub-bins (sub = blockIdx&7, XCD proxy)
#define BK_SHIFT 6
#define BK_NODES 64
#define K_BUCK   ((N_NODES + BK_NODES - 1) / BK_NODES)   // 1563
#define CAP8     384      // per sub-bin; mean 160, sigma 12.6 -> 17 sigma headroom
#define NMAX     2048     // per bucket; mean 1280, sigma 36

typedef int v4i __attribute__((ext_vector_type(4)));

// ---------------- edge binning: [sub][bucket][CAP8] layout ----------------
// 4 edges per thread via int4 NT loads (streamed edges must not evict hot tail lines).
// pack: src (17 bits) | dst_local (6 bits) << 17

__global__ void k_bin8(const int* __restrict__ src, const int* __restrict__ dst,
                       int* __restrict__ cnt8, unsigned* __restrict__ bins8) {
    int e4 = blockIdx.x * blockDim.x + threadIdx.x;
    if (e4 >= N_EDGES / 4) return;
    v4i s4 = __builtin_nontemporal_load((const v4i*)src + e4);
    v4i d4 = __builtin_nontemporal_load((const v4i*)dst + e4);
    int sub = blockIdx.x & 7;
#pragma unroll
    for (int j = 0; j < 4; ++j) {
        int d = d4[j], s = s4[j];
        int b  = d >> BK_SHIFT;
        int dl = d & (BK_NODES - 1);
        int c  = sub * K_BUCK + b;       // sub-major: no cross-XCD line sharing
        int pos = atomicAdd(&cnt8[c], 1);
        if (pos < CAP8)
            bins8[(size_t)c * CAP8 + pos] = (unsigned)s | ((unsigned)dl << 17);
    }
}

// ---------------- per-bucket counting sort -> exact CSR + off/deg ----------------
// One block per bucket. All csr writes land in the bucket's own 8 KB window.

__global__ __launch_bounds__(256)
void k_sortfill(const int* __restrict__ cnt8, const unsigned* __restrict__ bins8,
                int* __restrict__ csr, int* __restrict__ off, int* __restrict__ deg) {
    __shared__ unsigned els[NMAX];
    __shared__ int scnt[8], sbase[9];
    __shared__ int h[64], nb[64], cur[64];
    const int t = threadIdx.x, b = blockIdx.x;

    if (t < 8) { int c = cnt8[t * K_BUCK + b]; scnt[t] = (c > CAP8) ? CAP8 : c; }
    if (t < 64) { h[t] = 0; cur[t] = 0; }
    __syncthreads();
    if (t == 0) {
        int r = 0;
        for (int s = 0; s < 8; ++s) {
            sbase[s] = r;
            r += scnt[s];
            if (r > NMAX) r = NMAX;      // safety clamp: els holds NMAX entries
        }
        sbase[8] = r;
    }
    __syncthreads();
    const int n = sbase[8];

    // stage the 8 sub-lists contiguously into LDS (NT: streamed once)
    for (int s = 0; s < 8; ++s) {
        const unsigned* bp = bins8 + (size_t)(s * K_BUCK + b) * CAP8;
        int c = sbase[s + 1] - sbase[s];     // clamped count
        int base = sbase[s];
        for (int i = t; i < c; i += 256)
            els[base + i] = __builtin_nontemporal_load(bp + i);
    }
    __syncthreads();
    // histogram over dst_local
    for (int i = t; i < n; i += 256) atomicAdd(&h[els[i] >> 17], 1);
    __syncthreads();
    if (t == 0) { int r = 0; for (int j = 0; j < 64; ++j) { nb[j] = r; r += h[j]; } }
    __syncthreads();
    // scatter into per-node contiguous ranges (bucket-local writes)
    const int cbase = b * NMAX;
    for (int i = t; i < n; i += 256) {
        unsigned p = els[i];
        int dl  = (int)(p >> 17);
        int pos = nb[dl] + atomicAdd(&cur[dl], 1);
        csr[cbase + pos] = (int)(p & 0x1FFFFu);
    }
    if (t < 64) {
        int node = (b << BK_SHIFT) + t;
        if (node < N_NODES) { off[node] = cbase + nb[t]; deg[node] = h[t]; }
    }
}

// ---------------- fused layer: private-reg gather-sum + transform + act + BN ----------------
// 320 threads = NPB nodes x R4 slices. No LDS atomics; LDS only for the handoff.

template<int F, bool RELU>
__global__ __launch_bounds__(320)
void k_agg_tf(const float* __restrict__ feat, const int* __restrict__ csr,
              const int* __restrict__ off, const int* __restrict__ deg,
              const float* __restrict__ w_rel, const float* __restrict__ w_root,
              const float* __restrict__ bias,
              const float* __restrict__ bn_g, const float* __restrict__ bn_b,
              const float* __restrict__ bn_m, const float* __restrict__ bn_v,
              float* __restrict__ h_out) {
    constexpr int R4  = F / 4;        // 8 (F=32) or 10 (F=40)
    constexpr int NPB = 320 / R4;     // 40 or 32 nodes per block
    constexpr int KO  = HID / R4;     // 5 or 4 outputs per thread
    constexpr int ST  = F + 4;        // LDS row stride: 16B-aligned, odd/4 bank skew

    __shared__ float accs[NPB][ST];
    __shared__ float xs[NPB][ST];
    __shared__ float wl[F * HID];
    __shared__ float wr[F * HID];
    __shared__ float bb[HID], sc[HID], sh[HID];

    const int t    = threadIdx.x;
    const int nl   = t / R4;
    const int f4   = t - nl * R4;
    const int node = blockIdx.x * NPB + nl;   // grids divide N_NODES exactly

    // stage weights + folded BN consts (overlaps with gather issue below)
    for (int i = t; i < F * HID; i += 320) { wl[i] = w_rel[i]; wr[i] = w_root[i]; }
    if (t < HID) {
        float s = bn_g[t] * rsqrtf(bn_v[t] + 1e-5f);
        sc[t] = s; sh[t] = bn_b[t] - bn_m[t] * s; bb[t] = bias[t];
    }

    // stage this thread's x slice (coalesced) — serves the root term
    const float4* feat4 = (const float4*)feat;
    float4 xv = feat4[(size_t)node * R4 + f4];
    *(float4*)&xs[nl][f4 * 4] = xv;

    // gather: private accumulator, 4-deep clamp+mask unroll; csr is NT (streamed,
    // must not evict the gather-hot feature table from L2)
    const int s0 = off[node];
    const int e0 = s0 + deg[node];
    float4 acc = make_float4(0.f, 0.f, 0.f, 0.f);
    for (int k = s0; k < e0; k += 4) {
        int i0 = __builtin_nontemporal_load(csr + k);
        int i1 = __builtin_nontemporal_load(csr + ((k + 1 < e0) ? k + 1 : e0 - 1));
        int i2 = __builtin_nontemporal_load(csr + ((k + 2 < e0) ? k + 2 : e0 - 1));
        int i3 = __builtin_nontemporal_load(csr + ((k + 3 < e0) ? k + 3 : e0 - 1));
        float m1 = (k + 1 < e0) ? 1.f : 0.f;
        float m2 = (k + 2 < e0) ? 1.f : 0.f;
        float m3 = (k + 3 < e0) ? 1.f : 0.f;
        float4 v0 = feat4[(size_t)i0 * R4 + f4];
        float4 v1 = feat4[(size_t)i1 * R4 + f4];
        float4 v2 = feat4[(size_t)i2 * R4 + f4];
        float4 v3 = feat4[(size_t)i3 * R4 + f4];
        acc.x += v0.x;      acc.y += v0.y;      acc.z += v0.z;      acc.w += v0.w;
        acc.x += m1 * v1.x; acc.y += m1 * v1.y; acc.z += m1 * v1.z; acc.w += m1 * v1.w;
        acc.x += m2 * v2.x; acc.y += m2 * v2.y; acc.z += m2 * v2.z; acc.w += m2 * v2.w;
        acc.x += m3 * v3.x; acc.y += m3 * v3.y; acc.z += m3 * v3.z; acc.w += m3 * v3.w;
    }
    *(float4*)&accs[nl][f4 * 4] = acc;
    __syncthreads();

    // transform: same thread -> outputs j = f4*KO .. f4*KO+KO-1 (contiguous per node)
    float o[KO];
#pragma unroll
    for (int k2 = 0; k2 < KO; ++k2) o[k2] = bb[f4 * KO + k2];
    for (int i = 0; i < F; ++i) {
        float aa = accs[nl][i];
        float xa = xs[nl][i];
        const float* wli = &wl[i * HID + f4 * KO];
        const float* wri = &wr[i * HID + f4 * KO];
#pragma unroll
        for (int k2 = 0; k2 < KO; ++k2)
            o[k2] += aa * wli[k2] + xa * wri[k2];
    }
#pragma unroll
    for (int k2 = 0; k2 < KO; ++k2) {
        float v = o[k2];
        if (RELU) v = fmaxf(v, 0.f);
        o[k2] = sc[f4 * KO + k2] * v + sh[f4 * KO + k2];
    }
    float* op = h_out + (size_t)node * HID + f4 * KO;
#pragma unroll
    for (int k2 = 0; k2 < KO; ++k2) op[k2] = o[k2];
}

// ---------------- pool + head: one block (256 thr) per graph ----------------

__global__ __launch_bounds__(256)
void k_pool_head(const float* __restrict__ h, const int* __restrict__ batch,
                 const float* __restrict__ wl1, const float* __restrict__ bl1,
                 const float* __restrict__ wl2, const float* __restrict__ bl2,
                 float* __restrict__ out) {
    int g = blockIdx.x;
    int lo = 0, hi = N_NODES;
    while (lo < hi) { int mid = (lo + hi) >> 1; if (batch[mid] < g) lo = mid + 1; else hi = mid; }
    int start = lo;
    hi = N_NODES;
    while (lo < hi) { int mid = (lo + hi) >> 1; if (batch[mid] < g + 1) lo = mid + 1; else hi = mid; }
    int end = lo;

    __shared__ float red[25][44];
    __shared__ float gm[HID];
    __shared__ float l1[10];
    int t = threadIdx.x;
    int grp = t / 10, j4 = t - grp * 10;
    if (t < 250) {
        float4 m4 = make_float4(-INFINITY, -INFINITY, -INFINITY, -INFINITY);
        for (int r = start + grp; r < end; r += 25) {
            float4 v = ((const float4*)(h + (size_t)r * HID))[j4];
            m4.x = fmaxf(m4.x, v.x); m4.y = fmaxf(m4.y, v.y);
            m4.z = fmaxf(m4.z, v.z); m4.w = fmaxf(m4.w, v.w);
        }
        *((float4*)&red[grp][j4 * 4]) = m4;
    }
    __syncthreads();
    if (t < HID) {
        float m = -INFINITY;
#pragma unroll
        for (int g2 = 0; g2 < 25; ++g2) m = fmaxf(m, red[g2][t]);
        gm[t] = isfinite(m) ? m : 0.f;   // empty-graph guard
    }
    __syncthreads();
    if (t < 10) {
        float acc = bl1[t];
#pragma unroll
        for (int i = 0; i < HID; ++i) acc += gm[i] * wl1[i * 10 + t];
        l1[t] = fmaxf(acc, 0.f);
    }
    __syncthreads();
    if (t == 0) {
        float acc = bl2[0];
#pragma unroll
        for (int i = 0; i < 10; ++i) acc += l1[i] * wl2[i];
        out[g] = 1.f / (1.f + expf(-acc));
    }
}

// ---------------- launch ----------------

extern "C" void kernel_launch(void* const* d_in, const int* in_sizes, int n_in,
                              void* d_out, int out_size, void* d_ws, size_t ws_size,
                              hipStream_t stream) {
    const float* x       = (const float*)d_in[0];
    const int*   ei      = (const int*)d_in[1];
    const int*   src     = ei;              // edge_index[0]
    const int*   dst     = ei + N_EDGES;    // edge_index[1]
    const int*   batch   = (const int*)d_in[3];
    const float* w1_rel  = (const float*)d_in[5];
    const float* w1_root = (const float*)d_in[6];
    const float* b1      = (const float*)d_in[7];
    const float* w2_rel  = (const float*)d_in[8];
    const float* w2_root = (const float*)d_in[9];
    const float* b2      = (const float*)d_in[10];
    const float* w3_rel  = (const float*)d_in[11];
    const float* w3_root = (const float*)d_in[12];
    const float* b3      = (const float*)d_in[13];
    const float* bn1_g = (const float*)d_in[14], *bn1_b = (const float*)d_in[15];
    const float* bn1_m = (const float*)d_in[16], *bn1_v = (const float*)d_in[17];
    const float* bn2_g = (const float*)d_in[18], *bn2_b = (const float*)d_in[19];
    const float* bn2_m = (const float*)d_in[20], *bn2_v = (const float*)d_in[21];
    const float* bn3_g = (const float*)d_in[22], *bn3_b = (const float*)d_in[23];
    const float* bn3_m = (const float*)d_in[24], *bn3_v = (const float*)d_in[25];
    const float* wl1 = (const float*)d_in[26], *bl1 = (const float*)d_in[27];
    const float* wl2 = (const float*)d_in[28], *bl2 = (const float*)d_in[29];
    float* out = (float*)d_out;

    // workspace layout (~65 MB)
    char* ws = (char*)d_ws;
    size_t o = 0;
    auto take = [&](size_t bytes) -> void* {
        void* p = ws + o;
        o = (o + bytes + 255) & ~(size_t)255;
        return p;
    };
    int*      cnt8  = (int*)take((size_t)K_BUCK * 8 * sizeof(int));
    unsigned* bins8 = (unsigned*)take((size_t)K_BUCK * 8 * CAP8 * sizeof(unsigned));
    int*      csr   = (int*)take((size_t)K_BUCK * NMAX * sizeof(int));
    int*      off   = (int*)take((size_t)N_NODES * sizeof(int));
    int*      deg   = (int*)take((size_t)N_NODES * sizeof(int));
    float*    hA    = (float*)take((size_t)N_NODES * HID * sizeof(float));
    float*    hB    = (float*)take((size_t)N_NODES * HID * sizeof(float));

    hipMemsetAsync(cnt8, 0, (size_t)K_BUCK * 8 * sizeof(int), stream);
    k_bin8<<<(N_EDGES / 4 + 255) / 256, 256, 0, stream>>>(src, dst, cnt8, bins8);
    k_sortfill<<<K_BUCK, 256, 0, stream>>>(cnt8, bins8, csr, off, deg);

    // layer 1: F=32 -> 40, relu then bn   (2500 blocks x 40 nodes)
    k_agg_tf<32, true><<<N_NODES / 40, 320, 0, stream>>>(
        x, csr, off, deg, w1_rel, w1_root, b1, bn1_g, bn1_b, bn1_m, bn1_v, hA);
    // layer 2: 40 -> 40, relu then bn     (3125 blocks x 32 nodes)
    k_agg_tf<40, true><<<N_NODES / 32, 320, 0, stream>>>(
        hA, csr, off, deg, w2_rel, w2_root, b2, bn2_g, bn2_b, bn2_m, bn2_v, hB);
    // layer 3: 40 -> 40, bn only
    k_agg_tf<40, false><<<N_NODES / 32, 320, 0, stream>>>(
        hB, csr, off, deg, w3_rel, w3_root, b3, bn3_g, bn3_b, bn3_m, bn3_v, hA);

    // global max pool + MLP head + sigmoid
    k_pool_head<<<N_GRAPHS, 256, 0, stream>>>(hA, batch, wl1, bl1, wl2, bl2, out);
}

// Round 15
// 415.499 us; speedup vs baseline: 1.0351x; 1.0351x over previous
//
#include <hip/hip_runtime.h>
#include <math.h>

// Problem constants (from setup_inputs)
#define N_NODES  100000
#define N_EDGES  2000000
#define HID      40
#define N_GRAPHS 512

// dst-bucketing: 64 nodes per bucket, 8 sub-bins keyed by the REAL XCD id
#define BK_SHIFT 6
#define BK_NODES 64
#define K_BUCK   ((N_NODES + BK_NODES - 1) / BK_NODES)   // 1563
#define CAP8     384      // per sub-bin; mean 160 (balanced dispatch), big headroom
#define NMAX     2048     // per bucket staged entries; mean 1280, sigma 36
#define NMAX_PAD 2560     // csr slots per bucket: 2048 + 64 nodes x 7 pad, 8-aligned

typedef int v4i __attribute__((ext_vector_type(4)));

// ---------------- edge binning: [sub][bucket][CAP8], sub = hardware XCD id ----------------
// XCD-private slices: tail lines + counters only ever touched by one L2.
// pack: src (17 bits) | dst_local (6 bits) << 17

__global__ void k_bin8(const int* __restrict__ src, const int* __restrict__ dst,
                       int* __restrict__ cnt8, unsigned* __restrict__ bins8) {
    int e4 = blockIdx.x * blockDim.x + threadIdx.x;
    if (e4 >= N_EDGES / 4) return;
    unsigned xcc;
    asm volatile("s_getreg_b32 %0, hwreg(HW_REG_XCC_ID)" : "=s"(xcc));
    int sub = (int)(xcc & 7u);
    v4i s4 = __builtin_nontemporal_load((const v4i*)src + e4);
    v4i d4 = __builtin_nontemporal_load((const v4i*)dst + e4);
#pragma unroll
    for (int j = 0; j < 4; ++j) {
        int d = d4[j], s = s4[j];
        int b  = d >> BK_SHIFT;
        int dl = d & (BK_NODES - 1);
        int c  = sub * K_BUCK + b;       // sub-major: XCD-private lines
        int pos = atomicAdd(&cnt8[c], 1);
        if (pos < CAP8)
            bins8[(size_t)c * CAP8 + pos] = (unsigned)s | ((unsigned)dl << 17);
    }
}

// ---------------- per-bucket counting sort -> 8-aligned CSR + off/deg ----------------
// One block per bucket. Per-node ranges rounded to 8; pad entries = node 0 (masked later).

__global__ __launch_bounds__(256)
void k_sortfill(const int* __restrict__ cnt8, const unsigned* __restrict__ bins8,
                int* __restrict__ csr, int* __restrict__ off, int* __restrict__ deg) {
    __shared__ unsigned els[NMAX];
    __shared__ int scnt[8], sbase[9];
    __shared__ int h[64], nb[64], cur[64];
    const int t = threadIdx.x, b = blockIdx.x;

    if (t < 8) { int c = cnt8[t * K_BUCK + b]; scnt[t] = (c > CAP8) ? CAP8 : c; }
    if (t < 64) { h[t] = 0; cur[t] = 0; }
    __syncthreads();
    if (t == 0) {
        int r = 0;
        for (int s = 0; s < 8; ++s) {
            sbase[s] = r;
            r += scnt[s];
            if (r > NMAX) r = NMAX;      // safety clamp: els holds NMAX entries
        }
        sbase[8] = r;
    }
    __syncthreads();
    const int n = sbase[8];

    // stage the 8 sub-lists contiguously into LDS (NT: streamed once)
    for (int s = 0; s < 8; ++s) {
        const unsigned* bp = bins8 + (size_t)(s * K_BUCK + b) * CAP8;
        int c = sbase[s + 1] - sbase[s];     // clamped count
        int base = sbase[s];
        for (int i = t; i < c; i += 256)
            els[base + i] = __builtin_nontemporal_load(bp + i);
    }
    __syncthreads();
    // histogram over dst_local
    for (int i = t; i < n; i += 256) atomicAdd(&h[els[i] >> 17], 1);
    __syncthreads();
    if (t == 0) {
        int r = 0;
        for (int j = 0; j < 64; ++j) { nb[j] = r; r += (h[j] + 7) & ~7; }  // 8-aligned ranges
    }
    __syncthreads();
    // scatter into per-node contiguous ranges (bucket-local writes)
    const int cbase = b * NMAX_PAD;
    for (int i = t; i < n; i += 256) {
        unsigned p = els[i];
        int dl  = (int)(p >> 17);
        int pos = nb[dl] + atomicAdd(&cur[dl], 1);
        csr[cbase + pos] = (int)(p & 0x1FFFFu);
    }
    if (t < 64) {
        // zero-fill the pad slots (valid node 0; gather masks them out)
        int pe = nb[t] + ((h[t] + 7) & ~7);
        for (int i = nb[t] + h[t]; i < pe; ++i) csr[cbase + i] = 0;
        int node = (b << BK_SHIFT) + t;
        if (node < N_NODES) { off[node] = cbase + nb[t]; deg[node] = h[t]; }
    }
}

// ---------------- fused layer: private-reg gather-sum + transform + act + BN ----------------
// 320 threads = NPB nodes x R4 slices. 8-deep gather ILP via int4 csr loads.

template<int F, bool RELU>
__global__ __launch_bounds__(320)
void k_agg_tf(const float* __restrict__ feat, const int* __restrict__ csr,
              const int* __restrict__ off, const int* __restrict__ deg,
              const float* __restrict__ w_rel, const float* __restrict__ w_root,
              const float* __restrict__ bias,
              const float* __restrict__ bn_g, const float* __restrict__ bn_b,
              const float* __restrict__ bn_m, const float* __restrict__ bn_v,
              float* __restrict__ h_out) {
    constexpr int R4  = F / 4;        // 8 (F=32) or 10 (F=40)
    constexpr int NPB = 320 / R4;     // 40 or 32 nodes per block
    constexpr int KO  = HID / R4;     // 5 or 4 outputs per thread
    constexpr int ST  = F + 4;        // LDS row stride: 16B-aligned, odd/4 bank skew

    __shared__ float accs[NPB][ST];
    __shared__ float xs[NPB][ST];
    __shared__ float wl[F * HID];
    __shared__ float wr[F * HID];
    __shared__ float bb[HID], sc[HID], sh[HID];

    const int t    = threadIdx.x;
    const int nl   = t / R4;
    const int f4   = t - nl * R4;
    const int node = blockIdx.x * NPB + nl;   // grids divide N_NODES exactly

    // stage weights + folded BN consts (overlaps with gather issue below)
    for (int i = t; i < F * HID; i += 320) { wl[i] = w_rel[i]; wr[i] = w_root[i]; }
    if (t < HID) {
        float s = bn_g[t] * rsqrtf(bn_v[t] + 1e-5f);
        sc[t] = s; sh[t] = bn_b[t] - bn_m[t] * s; bb[t] = bias[t];
    }

    // stage this thread's x slice (coalesced) — serves the root term
    const float4* feat4 = (const float4*)feat;
    float4 xv = feat4[(size_t)node * R4 + f4];
    *(float4*)&xs[nl][f4 * 4] = xv;

    // gather: 8-deep ILP. csr range is 8-aligned + zero-padded, so two int4 NT
    // loads fetch 8 valid indices; pad entries (node 0) are masked out of the sum.
    const int s0 = off[node];
    const int e0 = s0 + deg[node];
    float4 acc = make_float4(0.f, 0.f, 0.f, 0.f);
    for (int k = s0; k < e0; k += 8) {
        v4i ca = __builtin_nontemporal_load((const v4i*)(csr + k));
        v4i cb = __builtin_nontemporal_load((const v4i*)(csr + k + 4));
        float4 v0 = feat4[(size_t)ca[0] * R4 + f4];
        float4 v1 = feat4[(size_t)ca[1] * R4 + f4];
        float4 v2 = feat4[(size_t)ca[2] * R4 + f4];
        float4 v3 = feat4[(size_t)ca[3] * R4 + f4];
        float4 v4_ = feat4[(size_t)cb[0] * R4 + f4];
        float4 v5 = feat4[(size_t)cb[1] * R4 + f4];
        float4 v6 = feat4[(size_t)cb[2] * R4 + f4];
        float4 v7 = feat4[(size_t)cb[3] * R4 + f4];
        float m1 = (k + 1 < e0) ? 1.f : 0.f;
        float m2 = (k + 2 < e0) ? 1.f : 0.f;
        float m3 = (k + 3 < e0) ? 1.f : 0.f;
        float m4 = (k + 4 < e0) ? 1.f : 0.f;
        float m5 = (k + 5 < e0) ? 1.f : 0.f;
        float m6 = (k + 6 < e0) ? 1.f : 0.f;
        float m7 = (k + 7 < e0) ? 1.f : 0.f;
        acc.x += v0.x;       acc.y += v0.y;       acc.z += v0.z;       acc.w += v0.w;
        acc.x += m1 * v1.x;  acc.y += m1 * v1.y;  acc.z += m1 * v1.z;  acc.w += m1 * v1.w;
        acc.x += m2 * v2.x;  acc.y += m2 * v2.y;  acc.z += m2 * v2.z;  acc.w += m2 * v2.w;
        acc.x += m3 * v3.x;  acc.y += m3 * v3.y;  acc.z += m3 * v3.z;  acc.w += m3 * v3.w;
        acc.x += m4 * v4_.x; acc.y += m4 * v4_.y; acc.z += m4 * v4_.z; acc.w += m4 * v4_.w;
        acc.x += m5 * v5.x;  acc.y += m5 * v5.y;  acc.z += m5 * v5.z;  acc.w += m5 * v5.w;
        acc.x += m6 * v6.x;  acc.y += m6 * v6.y;  acc.z += m6 * v6.z;  acc.w += m6 * v6.w;
        acc.x += m7 * v7.x;  acc.y += m7 * v7.y;  acc.z += m7 * v7.z;  acc.w += m7 * v7.w;
    }
    *(float4*)&accs[nl][f4 * 4] = acc;
    __syncthreads();

    // transform: same thread -> outputs j = f4*KO .. f4*KO+KO-1 (contiguous per node)
    float o[KO];
#pragma unroll
    for (int k2 = 0; k2 < KO; ++k2) o[k2] = bb[f4 * KO + k2];
    for (int i = 0; i < F; ++i) {
        float aa = accs[nl][i];
        float xa = xs[nl][i];
        const float* wli = &wl[i * HID + f4 * KO];
        const float* wri = &wr[i * HID + f4 * KO];
#pragma unroll
        for (int k2 = 0; k2 < KO; ++k2)
            o[k2] += aa * wli[k2] + xa * wri[k2];
    }
#pragma unroll
    for (int k2 = 0; k2 < KO; ++k2) {
        float v = o[k2];
        if (RELU) v = fmaxf(v, 0.f);
        o[k2] = sc[f4 * KO + k2] * v + sh[f4 * KO + k2];
    }
    float* op = h_out + (size_t)node * HID + f4 * KO;
#pragma unroll
    for (int k2 = 0; k2 < KO; ++k2) op[k2] = o[k2];
}

// ---------------- pool + head: one block (256 thr) per graph ----------------

__global__ __launch_bounds__(256)
void k_pool_head(const float* __restrict__ h, const int* __restrict__ batch,
                 const float* __restrict__ wl1, const float* __restrict__ bl1,
                 const float* __restrict__ wl2, const float* __restrict__ bl2,
                 float* __restrict__ out) {
    int g = blockIdx.x;
    int lo = 0, hi = N_NODES;
    while (lo < hi) { int mid = (lo + hi) >> 1; if (batch[mid] < g) lo = mid + 1; else hi = mid; }
    int start = lo;
    hi = N_NODES;
    while (lo < hi) { int mid = (lo + hi) >> 1; if (batch[mid] < g + 1) lo = mid + 1; else hi = mid; }
    int end = lo;

    __shared__ float red[25][44];
    __shared__ float gm[HID];
    __shared__ float l1[10];
    int t = threadIdx.x;
    int grp = t / 10, j4 = t - grp * 10;
    if (t < 250) {
        float4 m4 = make_float4(-INFINITY, -INFINITY, -INFINITY, -INFINITY);
        for (int r = start + grp; r < end; r += 25) {
            float4 v = ((const float4*)(h + (size_t)r * HID))[j4];
            m4.x = fmaxf(m4.x, v.x); m4.y = fmaxf(m4.y, v.y);
            m4.z = fmaxf(m4.z, v.z); m4.w = fmaxf(m4.w, v.w);
        }
        *((float4*)&red[grp][j4 * 4]) = m4;
    }
    __syncthreads();
    if (t < HID) {
        float m = -INFINITY;
#pragma unroll
        for (int g2 = 0; g2 < 25; ++g2) m = fmaxf(m, red[g2][t]);
        gm[t] = isfinite(m) ? m : 0.f;   // empty-graph guard
    }
    __syncthreads();
    if (t < 10) {
        float acc = bl1[t];
#pragma unroll
        for (int i = 0; i < HID; ++i) acc += gm[i] * wl1[i * 10 + t];
        l1[t] = fmaxf(acc, 0.f);
    }
    __syncthreads();
    if (t == 0) {
        float acc = bl2[0];
#pragma unroll
        for (int i = 0; i < 10; ++i) acc += l1[i] * wl2[i];
        out[g] = 1.f / (1.f + expf(-acc));
    }
}

// ---------------- launch ----------------

extern "C" void kernel_launch(void* const* d_in, const int* in_sizes, int n_in,
                              void* d_out, int out_size, void* d_ws, size_t ws_size,
                              hipStream_t stream) {
    const float* x       = (const float*)d_in[0];
    const int*   ei      = (const int*)d_in[1];
    const int*   src     = ei;              // edge_index[0]
    const int*   dst     = ei + N_EDGES;    // edge_index[1]
    const int*   batch   = (const int*)d_in[3];
    const float* w1_rel  = (const float*)d_in[5];
    const float* w1_root = (const float*)d_in[6];
    const float* b1      = (const float*)d_in[7];
    const float* w2_rel  = (const float*)d_in[8];
    const float* w2_root = (const float*)d_in[9];
    const float* b2      = (const float*)d_in[10];
    const float* w3_rel  = (const float*)d_in[11];
    const float* w3_root = (const float*)d_in[12];
    const float* b3      = (const float*)d_in[13];
    const float* bn1_g = (const float*)d_in[14], *bn1_b = (const float*)d_in[15];
    const float* bn1_m = (const float*)d_in[16], *bn1_v = (const float*)d_in[17];
    const float* bn2_g = (const float*)d_in[18], *bn2_b = (const float*)d_in[19];
    const float* bn2_m = (const float*)d_in[20], *bn2_v = (const float*)d_in[21];
    const float* bn3_g = (const float*)d_in[22], *bn3_b = (const float*)d_in[23];
    const float* bn3_m = (const float*)d_in[24], *bn3_v = (const float*)d_in[25];
    const float* wl1 = (const float*)d_in[26], *bl1 = (const float*)d_in[27];
    const float* wl2 = (const float*)d_in[28], *bl2 = (const float*)d_in[29];
    float* out = (float*)d_out;

    // workspace layout (~68 MB)
    char* ws = (char*)d_ws;
    size_t o = 0;
    auto take = [&](size_t bytes) -> void* {
        void* p = ws + o;
        o = (o + bytes + 255) & ~(size_t)255;
        return p;
    };
    int*      cnt8  = (int*)take((size_t)K_BUCK * 8 * sizeof(int));
    unsigned* bins8 = (unsigned*)take((size_t)K_BUCK * 8 * CAP8 * sizeof(unsigned));
    int*      csr   = (int*)take((size_t)K_BUCK * NMAX_PAD * sizeof(int));
    int*      off   = (int*)take((size_t)N_NODES * sizeof(int));
    int*      deg   = (int*)take((size_t)N_NODES * sizeof(int));
    float*    hA    = (float*)take((size_t)N_NODES * HID * sizeof(float));
    float*    hB    = (float*)take((size_t)N_NODES * HID * sizeof(float));

    hipMemsetAsync(cnt8, 0, (size_t)K_BUCK * 8 * sizeof(int), stream);
    k_bin8<<<(N_EDGES / 4 + 255) / 256, 256, 0, stream>>>(src, dst, cnt8, bins8);
    k_sortfill<<<K_BUCK, 256, 0, stream>>>(cnt8, bins8, csr, off, deg);

    // layer 1: F=32 -> 40, relu then bn   (2500 blocks x 40 nodes)
    k_agg_tf<32, true><<<N_NODES / 40, 320, 0, stream>>>(
        x, csr, off, deg, w1_rel, w1_root, b1, bn1_g, bn1_b, bn1_m, bn1_v, hA);
    // layer 2: 40 -> 40, relu then bn     (3125 blocks x 32 nodes)
    k_agg_tf<40, true><<<N_NODES / 32, 320, 0, stream>>>(
        hA, csr, off, deg, w2_rel, w2_root, b2, bn2_g, bn2_b, bn2_m, bn2_v, hB);
    // layer 3: 40 -> 40, bn only
    k_agg_tf<40, false><<<N_NODES / 32, 320, 0, stream>>>(
        hB, csr, off, deg, w3_rel, w3_root, b3, bn3_g, bn3_b, bn3_m, bn3_v, hA);

    // global max pool + MLP head + sigmoid
    k_pool_head<<<N_GRAPHS, 256, 0, stream>>>(hA, batch, wl1, bl1, wl2, bl2, out);
}